// Round 6
// baseline (3370.485 us; speedup 1.0000x reference)
//
#include <hip/hip_runtime.h>
#include <math.h>

#define M_TOTAL 2048
#define N_TOTAL 1024
#define TSEQ    80
#define EMB_D   512
#define VOCAB   50000
#define BK      64

typedef __attribute__((ext_vector_type(8))) short bf16x8;
typedef __attribute__((ext_vector_type(4))) float f32x4;

__device__ __forceinline__ ushort f2bf(float f) {
    union { float f; unsigned u; } v; v.f = f;
    unsigned r = v.u + 0x7FFFu + ((v.u >> 16) & 1u);
    return (ushort)(r >> 16);
}
__device__ __forceinline__ float bf2f(ushort h) {
    union { unsigned u; float f; } v; v.u = ((unsigned)h) << 16;
    return v.f;
}
__device__ __forceinline__ void gload_lds16(const ushort* g, ushort* l) {
    __builtin_amdgcn_global_load_lds(
        (const __attribute__((address_space(1))) void*)g,
        (__attribute__((address_space(3))) void*)l, 16, 0, 0);
}
#define VM0()   asm volatile("s_waitcnt vmcnt(0)" ::: "memory")

// ---------------------------------------------------------------------------
// Fused per-step kernel. 128x128 tiles, 512 threads (8 waves, wave-tile 64x32),
// 2-phase double-buffered global_load_lds pipeline, XOR-swizzled both sides.
// Grid 256: bid = (layer<<7)|(m<<3)|n  ->  bid%8 == n  for all m/layer, so each
// XCD (round-robin bid%8) always touches the same 128-col weight strip:
// U1T/W2T/U2T slices (3 x 256 KB) stay L2-resident across all 80 launches.
//   layer 0: h1[i] = tanh(h1prev@U1 + xw[i] + b1)   (16 chunks, K=1024)
//   layer 1: h2n   = tanh(h1prev@W2 + h2c@U2 + b2)  (32 chunks, K=2048)
// ---------------------------------------------------------------------------
__global__ __launch_bounds__(512) void fused_step(
    ushort* __restrict__ xw_h1,
    const ushort* __restrict__ h1prev,
    const ushort* __restrict__ U1T, const float* __restrict__ b1,
    ushort* __restrict__ h2n, const ushort* __restrict__ h2c,
    const ushort* __restrict__ W2T, const ushort* __restrict__ U2T,
    const float* __restrict__ b2, int do_l1, int do_l2)
{
    __shared__ ushort As[2][128 * BK];   // 2 x 16 KB
    __shared__ ushort Bs[2][128 * BK];   // 2 x 16 KB
    const int tid = threadIdx.x;
    const int w = tid >> 6, l = tid & 63;
    const int wr = w >> 2, wc = w & 3;        // wave grid 2 x 4
    const int bid = blockIdx.x;
    const int layer = bid >> 7;
    const int rem = bid & 127;
    const int bm0 = (rem >> 3) << 7;          // 16 M-tiles of 128
    const int bn0 = (rem & 7) << 7;           // 8 N-tiles of 128 (== XCD id)

    if (layer ? !do_l2 : !do_l1) return;

    const int lr = l >> 3;
    const int se = ((l & 7) ^ lr) << 3;       // pre-swizzled source k-element

    auto stage = [&](const ushort* __restrict__ A, const ushort* __restrict__ B,
                     int k0, int buf) {
        #pragma unroll
        for (int j = 0; j < 2; ++j) {         // wave w stages rows w*16 .. +16
            const int rb = w * 16 + j * 8;
            gload_lds16(A + (size_t)(bm0 + rb + lr) * N_TOTAL + k0 + se,
                        &As[buf][rb * BK + l * 8]);
            gload_lds16(B + (size_t)(bn0 + rb + lr) * N_TOTAL + k0 + se,
                        &Bs[buf][rb * BK + l * 8]);
        }
    };

    f32x4 acc[4][2] = {};

    auto compute = [&](int buf) {
        #pragma unroll
        for (int kf = 0; kf < 2; ++kf) {
            const int ke = kf * 32 + (l >> 4) * 8;
            bf16x8 a[4], b[2];
            #pragma unroll
            for (int mf = 0; mf < 4; ++mf) {
                const int row = wr * 64 + mf * 16 + (l & 15);
                a[mf] = *(const bf16x8*)&As[buf][row * BK + (ke ^ ((row & 7) << 3))];
            }
            #pragma unroll
            for (int nf = 0; nf < 2; ++nf) {
                const int row = wc * 32 + nf * 16 + (l & 15);
                b[nf] = *(const bf16x8*)&Bs[buf][row * BK + (ke ^ ((row & 7) << 3))];
            }
            #pragma unroll
            for (int mf = 0; mf < 4; ++mf)
                #pragma unroll
                for (int nf = 0; nf < 2; ++nf)
                    acc[mf][nf] = __builtin_amdgcn_mfma_f32_16x16x32_bf16(
                        a[mf], b[nf], acc[mf][nf], 0, 0, 0);
        }
    };

    if (layer == 0) {
        stage(h1prev, U1T, 0, 0);
        VM0(); __syncthreads();
        int cur = 0;
        #pragma unroll
        for (int c = 0; c < 16; ++c) {
            if (c + 1 < 16) stage(h1prev, U1T, (c + 1) << 6, cur ^ 1);
            compute(cur);
            VM0(); __syncthreads();
            cur ^= 1;
        }
        #pragma unroll
        for (int nf = 0; nf < 2; ++nf) {
            const int col = bn0 + wc * 32 + nf * 16 + (l & 15);
            const float bz = b1[col];
            #pragma unroll
            for (int mf = 0; mf < 4; ++mf) {
                const int rb = bm0 + wr * 64 + mf * 16 + (l >> 4) * 4;
                #pragma unroll
                for (int r = 0; r < 4; ++r) {
                    const size_t idx = (size_t)(rb + r) * N_TOTAL + col;
                    xw_h1[idx] = f2bf(tanhf(acc[mf][nf][r] + bf2f(xw_h1[idx]) + bz));
                }
            }
        }
    } else {
        stage(h1prev, W2T, 0, 0);
        VM0(); __syncthreads();
        int cur = 0;
        #pragma unroll
        for (int c = 0; c < 16; ++c) {
            if (c + 1 < 16) stage(h1prev, W2T, (c + 1) << 6, cur ^ 1);
            else            stage(h2c,    U2T, 0,            cur ^ 1);
            compute(cur);
            VM0(); __syncthreads();
            cur ^= 1;
        }
        #pragma unroll
        for (int c = 0; c < 16; ++c) {
            if (c + 1 < 16) stage(h2c, U2T, (c + 1) << 6, cur ^ 1);
            compute(cur);
            VM0(); __syncthreads();
            cur ^= 1;
        }
        #pragma unroll
        for (int nf = 0; nf < 2; ++nf) {
            const int col = bn0 + wc * 32 + nf * 16 + (l & 15);
            const float bz = b2[col];
            #pragma unroll
            for (int mf = 0; mf < 4; ++mf) {
                const int rb = bm0 + wr * 64 + mf * 16 + (l >> 4) * 4;
                #pragma unroll
                for (int r = 0; r < 4; ++r)
                    h2n[(size_t)(rb + r) * N_TOTAL + col] =
                        f2bf(tanhf(acc[mf][nf][r] + bz));
            }
        }
    }
}

// ---------------------------------------------------------------------------
// XW1[t*2048+b][n] = embb[tokens[b][t]] @ W1^T. 128x128 tiles, 512 threads,
// same 2-phase pipeline; per-lane gather addresses for the A (embedding) tile.
// ---------------------------------------------------------------------------
__global__ __launch_bounds__(512) void xw1_gemm(
    ushort* __restrict__ outp,          // [163840][1024] bf16
    const ushort* __restrict__ embb,    // [50000][512] bf16
    const int* __restrict__ tok,        // [2048][80]
    const ushort* __restrict__ W1T)     // [1024][512] bf16
{
    __shared__ ushort As[2][128 * BK];
    __shared__ ushort Bs[2][128 * BK];
    const int tid = threadIdx.x;
    const int w = tid >> 6, l = tid & 63;
    const int wr = w >> 2, wc = w & 3;
    const int bid = blockIdx.x;
    const int bm0 = (bid >> 3) << 7;          // 1280 M-tiles
    const int bn0 = (bid & 7) << 7;           // 8 N-tiles (== XCD id)

    const int lr = l >> 3;
    const int se = ((l & 7) ^ lr) << 3;

    // gather rows: global M row -> (b, t) -> token
    const int rg0 = bm0 + w * 16 + lr;
    const int rg1 = rg0 + 8;
    const int tk0 = tok[(rg0 & (M_TOTAL - 1)) * TSEQ + (rg0 >> 11)];
    const int tk1 = tok[(rg1 & (M_TOTAL - 1)) * TSEQ + (rg1 >> 11)];
    const size_t ga0 = (size_t)tk0 * EMB_D + se;
    const size_t ga1 = (size_t)tk1 * EMB_D + se;

    auto stage = [&](int c, int buf) {
        const int k0 = c << 6;
        gload_lds16(embb + ga0 + k0, &As[buf][(w * 16 + 0) * BK + l * 8]);
        gload_lds16(embb + ga1 + k0, &As[buf][(w * 16 + 8) * BK + l * 8]);
        #pragma unroll
        for (int j = 0; j < 2; ++j) {
            const int rb = w * 16 + j * 8;
            gload_lds16(W1T + (size_t)(bn0 + rb + lr) * EMB_D + k0 + se,
                        &Bs[buf][rb * BK + l * 8]);
        }
    };

    f32x4 acc[4][2] = {};
    stage(0, 0);
    VM0(); __syncthreads();
    int cur = 0;
    #pragma unroll
    for (int c = 0; c < 8; ++c) {            // K = 512
        if (c + 1 < 8) stage(c + 1, cur ^ 1);
        #pragma unroll
        for (int kf = 0; kf < 2; ++kf) {
            const int ke = kf * 32 + (l >> 4) * 8;
            bf16x8 a[4], b[2];
            #pragma unroll
            for (int mf = 0; mf < 4; ++mf) {
                const int row = wr * 64 + mf * 16 + (l & 15);
                a[mf] = *(const bf16x8*)&As[cur][row * BK + (ke ^ ((row & 7) << 3))];
            }
            #pragma unroll
            for (int nf = 0; nf < 2; ++nf) {
                const int row = wc * 32 + nf * 16 + (l & 15);
                b[nf] = *(const bf16x8*)&Bs[cur][row * BK + (ke ^ ((row & 7) << 3))];
            }
            #pragma unroll
            for (int mf = 0; mf < 4; ++mf)
                #pragma unroll
                for (int nf = 0; nf < 2; ++nf)
                    acc[mf][nf] = __builtin_amdgcn_mfma_f32_16x16x32_bf16(
                        a[mf], b[nf], acc[mf][nf], 0, 0, 0);
        }
        VM0(); __syncthreads();
        cur ^= 1;
    }

    #pragma unroll
    for (int nf = 0; nf < 2; ++nf) {
        const int col = bn0 + wc * 32 + nf * 16 + (l & 15);
        #pragma unroll
        for (int mf = 0; mf < 4; ++mf) {
            const int rb = bm0 + wr * 64 + mf * 16 + (l >> 4) * 4;
            #pragma unroll
            for (int r = 0; r < 4; ++r)
                outp[(size_t)(rb + r) * N_TOTAL + col] = f2bf(acc[mf][nf][r]);
        }
    }
}

// emb fp32 -> bf16 (50000*512/8/256 = 12500 blocks)
__global__ __launch_bounds__(256) void emb_convert(
    ushort* __restrict__ dst, const float* __restrict__ src)
{
    const size_t i = ((size_t)blockIdx.x * 256 + threadIdx.x) * 8;
    const float4 v0 = *(const float4*)(src + i);
    const float4 v1 = *(const float4*)(src + i + 4);
    const unsigned w0 = f2bf(v0.x) | (f2bf(v0.y) << 16);
    const unsigned w1 = f2bf(v0.z) | (f2bf(v0.w) << 16);
    const unsigned w2 = f2bf(v1.x) | (f2bf(v1.y) << 16);
    const unsigned w3 = f2bf(v1.z) | (f2bf(v1.w) << 16);
    *(uint4*)(dst + i) = make_uint4(w0, w1, w2, w3);
}

// W [K][N] fp32 -> WT [N][K] bf16
__global__ __launch_bounds__(256) void transpose_convert(
    ushort* __restrict__ outT, const float* __restrict__ in, int K, int N)
{
    __shared__ float tile[64][65];
    const int tiles_n = N >> 6;
    const int k0 = (blockIdx.x / tiles_n) << 6;
    const int n0 = (blockIdx.x % tiles_n) << 6;
    const int tid = threadIdx.x;
    const int r = tid >> 4, c = (tid & 15) << 2;
    #pragma unroll
    for (int i = 0; i < 4; ++i) {
        const float4 v = *(const float4*)(in + (size_t)(k0 + r + i * 16) * N + n0 + c);
        tile[r + i * 16][c + 0] = v.x;
        tile[r + i * 16][c + 1] = v.y;
        tile[r + i * 16][c + 2] = v.z;
        tile[r + i * 16][c + 3] = v.w;
    }
    __syncthreads();
    const int n = tid >> 2, ks = (tid & 3) << 4;
    unsigned pk[8];
    #pragma unroll
    for (int j = 0; j < 8; ++j) {
        const unsigned lo = f2bf(tile[ks + 2 * j][n]);
        const unsigned hi = f2bf(tile[ks + 2 * j + 1][n]);
        pk[j] = lo | (hi << 16);
    }
    ushort* dst = outT + (size_t)(n0 + n) * K + k0 + ks;
    *(uint4*)(dst + 0) = make_uint4(pk[0], pk[1], pk[2], pk[3]);
    *(uint4*)(dst + 8) = make_uint4(pk[4], pk[5], pk[6], pk[7]);
}

__global__ __launch_bounds__(256) void out_kernel(
    float* __restrict__ out, const ushort* __restrict__ h2,
    const float* __restrict__ Wo, const float* __restrict__ bo)
{
    const int row  = blockIdx.x * 4 + (threadIdx.x >> 6);
    const int lane = threadIdx.x & 63;
    const ushort* hr = h2 + (size_t)row * N_TOTAL;
    float s = 0.f;
    for (int k = lane; k < N_TOTAL; k += 64)
        s += bf2f(hr[k]) * Wo[k];
    #pragma unroll
    for (int off = 32; off; off >>= 1)
        s += __shfl_down(s, off);
    if (lane == 0)
        out[row] = 1.f / (1.f + expf(-(s + bo[0])));
}

extern "C" void kernel_launch(void* const* d_in, const int* in_sizes, int n_in,
                              void* d_out, int out_size, void* d_ws, size_t ws_size,
                              hipStream_t stream) {
    const int*   tokens = (const int*)  d_in[0];
    const float* emb    = (const float*)d_in[1];
    const float* W1     = (const float*)d_in[2];
    const float* U1     = (const float*)d_in[3];
    const float* b1     = (const float*)d_in[4];
    const float* W2     = (const float*)d_in[5];
    const float* U2     = (const float*)d_in[6];
    const float* b2     = (const float*)d_in[7];
    const float* Wo     = (const float*)d_in[8];
    const float* bo     = (const float*)d_in[9];
    float* out = (float*)d_out;

    char* ws = (char*)d_ws;
    const size_t HB   = (size_t)M_TOTAL * N_TOTAL * sizeof(ushort);   // 4 MB
    const size_t SLAB = (size_t)M_TOTAL * N_TOTAL;                    // elems
    ushort* h1zero = (ushort*)(ws);
    ushort* h2a    = (ushort*)(ws + 1 * HB);
    ushort* h2b    = (ushort*)(ws + 2 * HB);
    size_t off = 3 * HB;
    ushort* W1T = (ushort*)(ws + off); off += (size_t)N_TOTAL * EMB_D   * 2;
    ushort* U1T = (ushort*)(ws + off); off += (size_t)N_TOTAL * N_TOTAL * 2;
    ushort* W2T = (ushort*)(ws + off); off += (size_t)N_TOTAL * N_TOTAL * 2;
    ushort* U2T = (ushort*)(ws + off); off += (size_t)N_TOTAL * N_TOTAL * 2;
    ushort* embb = (ushort*)(ws + off); off += (size_t)VOCAB * EMB_D * 2;
    ushort* XW1  = (ushort*)(ws + off);   // 80 slabs x 4 MB = 335.5 MB

    hipMemsetAsync(h1zero, 0, HB, stream);
    hipMemsetAsync(h2a,    0, HB, stream);

    emb_convert<<<dim3(12500), 256, 0, stream>>>(embb, emb);
    transpose_convert<<<dim3((EMB_D  / 64) * (N_TOTAL / 64)), 256, 0, stream>>>(W1T, W1, EMB_D,   N_TOTAL);
    transpose_convert<<<dim3((N_TOTAL / 64) * (N_TOTAL / 64)), 256, 0, stream>>>(U1T, U1, N_TOTAL, N_TOTAL);
    transpose_convert<<<dim3((N_TOTAL / 64) * (N_TOTAL / 64)), 256, 0, stream>>>(W2T, W2, N_TOTAL, N_TOTAL);
    transpose_convert<<<dim3((N_TOTAL / 64) * (N_TOTAL / 64)), 256, 0, stream>>>(U2T, U2, N_TOTAL, N_TOTAL);

    xw1_gemm<<<dim3((TSEQ * M_TOTAL / 128) * 8), 512, 0, stream>>>(XW1, embb, tokens, W1T);

    ushort* h2c = h2a; ushort* h2n = h2b;
    for (int i = 0; i <= TSEQ; ++i) {
        const int do_l1 = (i < TSEQ) ? 1 : 0;
        const int do_l2 = (i >= 1) ? 1 : 0;
        ushort* slab_i  = (i < TSEQ) ? (XW1 + (size_t)i * SLAB) : XW1;
        const ushort* h1prev = (i == 0) ? h1zero : (XW1 + (size_t)(i - 1) * SLAB);
        fused_step<<<dim3(256), 512, 0, stream>>>(
            slab_i, h1prev, U1T, b1, h2n, h2c, W2T, U2T, b2, do_l1, do_l2);
        if (i >= 1) { ushort* t = h2c; h2c = h2n; h2n = t; }
    }

    out_kernel<<<dim3(M_TOTAL / 4), dim3(256), 0, stream>>>(out, h2c, Wo, bo);
}

// Round 7
// 2428.197 us; speedup vs baseline: 1.3881x; 1.3881x over previous
//
#include <hip/hip_runtime.h>
#include <math.h>

#define M_TOTAL 2048
#define N_TOTAL 1024
#define TSEQ    80
#define EMB_D   512
#define VOCAB   50000
#define BK      64

typedef __attribute__((ext_vector_type(8))) short bf16x8;
typedef __attribute__((ext_vector_type(4))) float f32x4;

__device__ __forceinline__ ushort f2bf(float f) {
    union { float f; unsigned u; } v; v.f = f;
    unsigned r = v.u + 0x7FFFu + ((v.u >> 16) & 1u);
    return (ushort)(r >> 16);
}
__device__ __forceinline__ float bf2f(ushort h) {
    union { unsigned u; float f; } v; v.u = ((unsigned)h) << 16;
    return v.f;
}
__device__ __forceinline__ void gload_lds16(const ushort* g, ushort* l) {
    __builtin_amdgcn_global_load_lds(
        (const __attribute__((address_space(1))) void*)g,
        (__attribute__((address_space(3))) void*)l, 16, 0, 0);
}
#define VMC6()  asm volatile("s_waitcnt vmcnt(6)" ::: "memory")
#define VMC0()  asm volatile("s_waitcnt vmcnt(0)" ::: "memory")
#define SBAR()  __builtin_amdgcn_s_barrier()
#define SCHED0() __builtin_amdgcn_sched_barrier(0)

// ---------------------------------------------------------------------------
// Fused per-step kernel. 128x64 tiles, 256 thr (4 waves, wave-tile 64x32).
// Counted-vmcnt TRIPLE-buffered pipeline: per chunk
//   stage(c+1) [6 loads/thr] ; vmcnt(6) [chunk c landed, c+1 in flight] ;
//   s_barrier ; compute(c).
// Loads stay in flight across barriers; no vmcnt(0) in steady state.
// Grid 512: bid&7 == n>>1 pins each XCD to one 128-col weight strip
// (U1T/W2T/U2T slices stay L2-resident across all 80 launches).
//   layer 0 (NC=16): h1[i] = tanh(h1prev@U1 + xw[i] + b1)
//   layer 1 (NC=32): h2n   = tanh(h1prev@W2 + h2c@U2 + b2)
// ---------------------------------------------------------------------------
__global__ __launch_bounds__(256) void fused_step(
    ushort* __restrict__ xw_h1,
    const ushort* __restrict__ h1prev,
    const ushort* __restrict__ U1T, const float* __restrict__ b1,
    ushort* __restrict__ h2n, const ushort* __restrict__ h2c,
    const ushort* __restrict__ W2T, const ushort* __restrict__ U2T,
    const float* __restrict__ b2, int do_l1, int do_l2)
{
    __shared__ ushort As[3][128 * BK];   // 3 x 16 KB
    __shared__ ushort Bs[3][64 * BK];    // 3 x  8 KB   (72 KB total)
    const int tid = threadIdx.x;
    const int w = tid >> 6, l = tid & 63;
    const int wr = w >> 1, wc = w & 1;        // wave grid 2 x 2, tile 64x32
    const int bid = blockIdx.x;
    const int strip = bid & 7;                // XCD id == weight strip
    const int q = bid >> 3;
    const int layer = q & 1;
    const int rr = q >> 1;                    // 0..31
    const int n = strip * 2 + (rr & 1);       // 0..15
    const int m = rr >> 1;                    // 0..15
    const int bm0 = m << 7;
    const int bn0 = n << 6;

    if (layer ? !do_l2 : !do_l1) return;

    const int lr = l >> 3;
    const int se = ((l & 7) ^ lr) << 3;       // pre-swizzled source k-elem

    auto stage = [&](const ushort* __restrict__ A, const ushort* __restrict__ B,
                     int k0, int buf) {
        #pragma unroll
        for (int j = 0; j < 4; ++j) {         // A rows w*32+j*8 .. +8
            const int rb = w * 32 + j * 8;
            gload_lds16(A + (size_t)(bm0 + rb + lr) * N_TOTAL + k0 + se,
                        &As[buf][rb * BK + l * 8]);
        }
        #pragma unroll
        for (int j = 0; j < 2; ++j) {         // B rows w*16+j*8 .. +8
            const int rb = w * 16 + j * 8;
            gload_lds16(B + (size_t)(bn0 + rb + lr) * N_TOTAL + k0 + se,
                        &Bs[buf][rb * BK + l * 8]);
        }
    };

    f32x4 acc[4][2] = {};

    auto compute = [&](int buf) {
        #pragma unroll
        for (int kf = 0; kf < 2; ++kf) {
            const int ke = kf * 32 + (l >> 4) * 8;
            bf16x8 a[4], b[2];
            #pragma unroll
            for (int mf = 0; mf < 4; ++mf) {
                const int row = wr * 64 + mf * 16 + (l & 15);
                a[mf] = *(const bf16x8*)&As[buf][row * BK + (ke ^ ((row & 7) << 3))];
            }
            #pragma unroll
            for (int nf = 0; nf < 2; ++nf) {
                const int row = wc * 32 + nf * 16 + (l & 15);
                b[nf] = *(const bf16x8*)&Bs[buf][row * BK + (ke ^ ((row & 7) << 3))];
            }
            #pragma unroll
            for (int mf = 0; mf < 4; ++mf)
                #pragma unroll
                for (int nf = 0; nf < 2; ++nf)
                    acc[mf][nf] = __builtin_amdgcn_mfma_f32_16x16x32_bf16(
                        a[mf], b[nf], acc[mf][nf], 0, 0, 0);
        }
    };

    if (layer == 0) {
        auto stage_cc = [&](int cc, int buf) { stage(h1prev, U1T, cc << 6, buf); };
        stage_cc(0, 0);
        int bufc = 0;
        #pragma unroll
        for (int c = 0; c < 16; ++c) {
            int bufn = bufc + 1; if (bufn == 3) bufn = 0;
            if (c + 1 < 16) { stage_cc(c + 1, bufn); VMC6(); }
            else            { VMC0(); }
            SBAR(); SCHED0();
            compute(bufc);
            bufc = bufn;
        }
        #pragma unroll
        for (int nf = 0; nf < 2; ++nf) {
            const int col = bn0 + wc * 32 + nf * 16 + (l & 15);
            const float bz = b1[col];
            #pragma unroll
            for (int mf = 0; mf < 4; ++mf) {
                const int rb = bm0 + wr * 64 + mf * 16 + (l >> 4) * 4;
                #pragma unroll
                for (int r = 0; r < 4; ++r) {
                    const size_t idx = (size_t)(rb + r) * N_TOTAL + col;
                    xw_h1[idx] = f2bf(tanhf(acc[mf][nf][r] + bf2f(xw_h1[idx]) + bz));
                }
            }
        }
    } else {
        auto stage_cc = [&](int cc, int buf) {
            if (cc < 16) stage(h1prev, W2T, cc << 6, buf);
            else         stage(h2c,    U2T, (cc - 16) << 6, buf);
        };
        stage_cc(0, 0);
        int bufc = 0;
        #pragma unroll
        for (int c = 0; c < 32; ++c) {
            int bufn = bufc + 1; if (bufn == 3) bufn = 0;
            if (c + 1 < 32) { stage_cc(c + 1, bufn); VMC6(); }
            else            { VMC0(); }
            SBAR(); SCHED0();
            compute(bufc);
            bufc = bufn;
        }
        #pragma unroll
        for (int nf = 0; nf < 2; ++nf) {
            const int col = bn0 + wc * 32 + nf * 16 + (l & 15);
            const float bz = b2[col];
            #pragma unroll
            for (int mf = 0; mf < 4; ++mf) {
                const int rb = bm0 + wr * 64 + mf * 16 + (l >> 4) * 4;
                #pragma unroll
                for (int r = 0; r < 4; ++r)
                    h2n[(size_t)(rb + r) * N_TOTAL + col] =
                        f2bf(tanhf(acc[mf][nf][r] + bz));
            }
        }
    }
}

// ---------------------------------------------------------------------------
// XW1[t*2048+b][n] = embb[tokens[b][t]] @ W1^T. Same pipelined template,
// 128x64 tiles, NC=8 (K=512), per-lane gather addresses for the A tile.
// ---------------------------------------------------------------------------
__global__ __launch_bounds__(256) void xw1_gemm(
    ushort* __restrict__ outp,          // [163840][1024] bf16
    const ushort* __restrict__ embb,    // [50000][512] bf16
    const int* __restrict__ tok,        // [2048][80]
    const ushort* __restrict__ W1T)     // [1024][512] bf16
{
    __shared__ ushort As[3][128 * BK];
    __shared__ ushort Bs[3][64 * BK];
    const int tid = threadIdx.x;
    const int w = tid >> 6, l = tid & 63;
    const int wr = w >> 1, wc = w & 1;
    const int bid = blockIdx.x;
    const int strip = bid & 7;
    const int q = bid >> 3;                   // 0..2559
    const int n = strip * 2 + (q & 1);        // 0..15
    const int m = q >> 1;                     // 0..1279
    const int bm0 = m << 7;
    const int bn0 = n << 6;

    const int lr = l >> 3;
    const int se = ((l & 7) ^ lr) << 3;

    // 4 gather rows per thread
    size_t ga[4];
    #pragma unroll
    for (int j = 0; j < 4; ++j) {
        const int rg = bm0 + w * 32 + j * 8 + lr;
        const int token = tok[(rg & (M_TOTAL - 1)) * TSEQ + (rg >> 11)];
        ga[j] = (size_t)token * EMB_D + se;
    }

    auto stage = [&](int cc, int buf) {
        const int k0 = cc << 6;
        #pragma unroll
        for (int j = 0; j < 4; ++j)
            gload_lds16(embb + ga[j] + k0, &As[buf][(w * 32 + j * 8) * BK + l * 8]);
        #pragma unroll
        for (int j = 0; j < 2; ++j) {
            const int rb = w * 16 + j * 8;
            gload_lds16(W1T + (size_t)(bn0 + rb + lr) * EMB_D + k0 + se,
                        &Bs[buf][rb * BK + l * 8]);
        }
    };

    f32x4 acc[4][2] = {};
    stage(0, 0);
    int bufc = 0;
    #pragma unroll
    for (int c = 0; c < 8; ++c) {
        int bufn = bufc + 1; if (bufn == 3) bufn = 0;
        if (c + 1 < 8) { stage(c + 1, bufn); VMC6(); }
        else           { VMC0(); }
        SBAR(); SCHED0();
        #pragma unroll
        for (int kf = 0; kf < 2; ++kf) {
            const int ke = kf * 32 + (l >> 4) * 8;
            bf16x8 a[4], b[2];
            #pragma unroll
            for (int mf = 0; mf < 4; ++mf) {
                const int row = wr * 64 + mf * 16 + (l & 15);
                a[mf] = *(const bf16x8*)&As[bufc][row * BK + (ke ^ ((row & 7) << 3))];
            }
            #pragma unroll
            for (int nf = 0; nf < 2; ++nf) {
                const int row = wc * 32 + nf * 16 + (l & 15);
                b[nf] = *(const bf16x8*)&Bs[bufc][row * BK + (ke ^ ((row & 7) << 3))];
            }
            #pragma unroll
            for (int mf = 0; mf < 4; ++mf)
                #pragma unroll
                for (int nf = 0; nf < 2; ++nf)
                    acc[mf][nf] = __builtin_amdgcn_mfma_f32_16x16x32_bf16(
                        a[mf], b[nf], acc[mf][nf], 0, 0, 0);
        }
        bufc = bufn;
    }

    #pragma unroll
    for (int nf = 0; nf < 2; ++nf) {
        const int col = bn0 + wc * 32 + nf * 16 + (l & 15);
        #pragma unroll
        for (int mf = 0; mf < 4; ++mf) {
            const int rb = bm0 + wr * 64 + mf * 16 + (l >> 4) * 4;
            #pragma unroll
            for (int r = 0; r < 4; ++r)
                outp[(size_t)(rb + r) * N_TOTAL + col] = f2bf(acc[mf][nf][r]);
        }
    }
}

// emb fp32 -> bf16 (50000*512/8/256 = 12500 blocks)
__global__ __launch_bounds__(256) void emb_convert(
    ushort* __restrict__ dst, const float* __restrict__ src)
{
    const size_t i = ((size_t)blockIdx.x * 256 + threadIdx.x) * 8;
    const float4 v0 = *(const float4*)(src + i);
    const float4 v1 = *(const float4*)(src + i + 4);
    const unsigned w0 = f2bf(v0.x) | (f2bf(v0.y) << 16);
    const unsigned w1 = f2bf(v0.z) | (f2bf(v0.w) << 16);
    const unsigned w2 = f2bf(v1.x) | (f2bf(v1.y) << 16);
    const unsigned w3 = f2bf(v1.z) | (f2bf(v1.w) << 16);
    *(uint4*)(dst + i) = make_uint4(w0, w1, w2, w3);
}

// W [K][N] fp32 -> WT [N][K] bf16
__global__ __launch_bounds__(256) void transpose_convert(
    ushort* __restrict__ outT, const float* __restrict__ in, int K, int N)
{
    __shared__ float tile[64][65];
    const int tiles_n = N >> 6;
    const int k0 = (blockIdx.x / tiles_n) << 6;
    const int n0 = (blockIdx.x % tiles_n) << 6;
    const int tid = threadIdx.x;
    const int r = tid >> 4, c = (tid & 15) << 2;
    #pragma unroll
    for (int i = 0; i < 4; ++i) {
        const float4 v = *(const float4*)(in + (size_t)(k0 + r + i * 16) * N + n0 + c);
        tile[r + i * 16][c + 0] = v.x;
        tile[r + i * 16][c + 1] = v.y;
        tile[r + i * 16][c + 2] = v.z;
        tile[r + i * 16][c + 3] = v.w;
    }
    __syncthreads();
    const int n = tid >> 2, ks = (tid & 3) << 4;
    unsigned pk[8];
    #pragma unroll
    for (int j = 0; j < 8; ++j) {
        const unsigned lo = f2bf(tile[ks + 2 * j][n]);
        const unsigned hi = f2bf(tile[ks + 2 * j + 1][n]);
        pk[j] = lo | (hi << 16);
    }
    ushort* dst = outT + (size_t)(n0 + n) * K + k0 + ks;
    *(uint4*)(dst + 0) = make_uint4(pk[0], pk[1], pk[2], pk[3]);
    *(uint4*)(dst + 8) = make_uint4(pk[4], pk[5], pk[6], pk[7]);
}

__global__ __launch_bounds__(256) void out_kernel(
    float* __restrict__ out, const ushort* __restrict__ h2,
    const float* __restrict__ Wo, const float* __restrict__ bo)
{
    const int row  = blockIdx.x * 4 + (threadIdx.x >> 6);
    const int lane = threadIdx.x & 63;
    const ushort* hr = h2 + (size_t)row * N_TOTAL;
    float s = 0.f;
    for (int k = lane; k < N_TOTAL; k += 64)
        s += bf2f(hr[k]) * Wo[k];
    #pragma unroll
    for (int off = 32; off; off >>= 1)
        s += __shfl_down(s, off);
    if (lane == 0)
        out[row] = 1.f / (1.f + expf(-(s + bo[0])));
}

extern "C" void kernel_launch(void* const* d_in, const int* in_sizes, int n_in,
                              void* d_out, int out_size, void* d_ws, size_t ws_size,
                              hipStream_t stream) {
    const int*   tokens = (const int*)  d_in[0];
    const float* emb    = (const float*)d_in[1];
    const float* W1     = (const float*)d_in[2];
    const float* U1     = (const float*)d_in[3];
    const float* b1     = (const float*)d_in[4];
    const float* W2     = (const float*)d_in[5];
    const float* U2     = (const float*)d_in[6];
    const float* b2     = (const float*)d_in[7];
    const float* Wo     = (const float*)d_in[8];
    const float* bo     = (const float*)d_in[9];
    float* out = (float*)d_out;

    char* ws = (char*)d_ws;
    const size_t HB   = (size_t)M_TOTAL * N_TOTAL * sizeof(ushort);   // 4 MB
    const size_t SLAB = (size_t)M_TOTAL * N_TOTAL;                    // elems
    ushort* h1zero = (ushort*)(ws);
    ushort* h2a    = (ushort*)(ws + 1 * HB);
    ushort* h2b    = (ushort*)(ws + 2 * HB);
    size_t off = 3 * HB;
    ushort* W1T = (ushort*)(ws + off); off += (size_t)N_TOTAL * EMB_D   * 2;
    ushort* U1T = (ushort*)(ws + off); off += (size_t)N_TOTAL * N_TOTAL * 2;
    ushort* W2T = (ushort*)(ws + off); off += (size_t)N_TOTAL * N_TOTAL * 2;
    ushort* U2T = (ushort*)(ws + off); off += (size_t)N_TOTAL * N_TOTAL * 2;
    ushort* embb = (ushort*)(ws + off); off += (size_t)VOCAB * EMB_D * 2;
    ushort* XW1  = (ushort*)(ws + off);   // 80 slabs x 4 MB = 335.5 MB

    hipMemsetAsync(h1zero, 0, HB, stream);
    hipMemsetAsync(h2a,    0, HB, stream);

    emb_convert<<<dim3(12500), 256, 0, stream>>>(embb, emb);
    transpose_convert<<<dim3((EMB_D  / 64) * (N_TOTAL / 64)), 256, 0, stream>>>(W1T, W1, EMB_D,   N_TOTAL);
    transpose_convert<<<dim3((N_TOTAL / 64) * (N_TOTAL / 64)), 256, 0, stream>>>(U1T, U1, N_TOTAL, N_TOTAL);
    transpose_convert<<<dim3((N_TOTAL / 64) * (N_TOTAL / 64)), 256, 0, stream>>>(W2T, W2, N_TOTAL, N_TOTAL);
    transpose_convert<<<dim3((N_TOTAL / 64) * (N_TOTAL / 64)), 256, 0, stream>>>(U2T, U2, N_TOTAL, N_TOTAL);

    xw1_gemm<<<dim3((TSEQ * M_TOTAL / 128) * 16), 256, 0, stream>>>(XW1, embb, tokens, W1T);

    ushort* h2c = h2a; ushort* h2n = h2b;
    for (int i = 0; i <= TSEQ; ++i) {
        const int do_l1 = (i < TSEQ) ? 1 : 0;
        const int do_l2 = (i >= 1) ? 1 : 0;
        ushort* slab_i  = (i < TSEQ) ? (XW1 + (size_t)i * SLAB) : XW1;
        const ushort* h1prev = (i == 0) ? h1zero : (XW1 + (size_t)(i - 1) * SLAB);
        fused_step<<<dim3(512), 256, 0, stream>>>(
            slab_i, h1prev, U1T, b1, h2n, h2c, W2T, U2T, b2, do_l1, do_l2);
        if (i >= 1) { ushort* t = h2c; h2c = h2n; h2n = t; }
    }

    out_kernel<<<dim3(M_TOTAL / 4), dim3(256), 0, stream>>>(out, h2c, Wo, bo);
}